// Round 1
// baseline (1166.948 us; speedup 1.0000x reference)
//
#include <hip/hip_runtime.h>
#include <stdint.h>

// Fused single-kernel top-k (k = 10% of N) by value over flat fp32.
// Pipeline (one persistent kernel, 6 device-wide barriers):
//   A: 12-bit histogram of sortable-u32 (LDS-privatized, 2 copies)   [read x]
//   scanA (all blocks redundantly) -> threshold bin b1, krem
//   B: scatter out=(v or 0), collect threshold-bin candidates (u,idx)
//      via LDS staging + 1 global atomic per block                    [read x (L3), write out]
//   C1/C2: radix over candidates' low 20 bits (10+10)  -> exact t_u, need_eq
//   D: write candidates with u > t_u; collect u == t_u into eq_list
//   E: stable tie-break (smallest indices) among eq elements
// Exactness identical to previous multi-kernel version; 10 dispatches -> 2.

#define BLK       256
#define MAXGRID   1024
#define NB1       4096   // top 12 bits
#define NB2       1024   // bits 19..10
#define NB3       1024   // bits 9..0
#define EQ_CAP    65536
#define STAGE_CAP 4096

__device__ __forceinline__ unsigned f2u(float x) {
    unsigned b = __float_as_uint(x);
    return (b & 0x80000000u) ? ~b : (b | 0x80000000u);
}
__device__ __forceinline__ float u2f(unsigned u) {
    return __uint_as_float((u & 0x80000000u) ? (u & 0x7FFFFFFFu) : ~u);
}

// Device-wide barrier. Release: __syncthreads (drains vmcnt) + threadfence
// (agent-scope: L2 writeback on gfx950). Acquire: threadfence after spin
// (L2 invalidate) so plain loads see other XCDs' data. Monotonic counter,
// no reset. Failsafe spin cap so a co-residency failure can't hang the bench.
__device__ __forceinline__ void gsync(unsigned* bar, unsigned target) {
    __syncthreads();
    if (threadIdx.x == 0) {
        __threadfence();
        __hip_atomic_fetch_add(bar, 1u, __ATOMIC_RELEASE, __HIP_MEMORY_SCOPE_AGENT);
        unsigned spins = 0u;
        while (__hip_atomic_load(bar, __ATOMIC_ACQUIRE, __HIP_MEMORY_SCOPE_AGENT) < target) {
            __builtin_amdgcn_s_sleep(2);
            if (++spins > 8000000u) break;  // ~1s failsafe; normal waits are µs
        }
        __threadfence();
    }
    __syncthreads();
}

__device__ __forceinline__ unsigned block_exscan256(unsigned v,
                                                    volatile unsigned* lds,
                                                    int tid)
{
    lds[tid] = v;
    __syncthreads();
    for (int off = 1; off < 256; off <<= 1) {
        unsigned t = (tid >= off) ? lds[tid - off] : 0u;
        __syncthreads();
        lds[tid] += t;
        __syncthreads();
    }
    unsigned incl = lds[tid];
    return incl - v;
}

__global__ void __launch_bounds__(BLK, 4)
topk_fused(const float* __restrict__ x, float* __restrict__ out,
           long long N, int n4, unsigned k,
           unsigned* __restrict__ sc,
           unsigned* __restrict__ hist_a, unsigned* __restrict__ hist_b,
           unsigned* __restrict__ hist_c,
           unsigned* __restrict__ cand_u, unsigned* __restrict__ cand_idx,
           unsigned cand_cap, unsigned* __restrict__ eq_list)
{
    __shared__ unsigned lh[2][NB1];   // 32 KB: hist copies / candidate staging
    __shared__ unsigned slds[256];
    __shared__ unsigned sb[4];

    const int tid = threadIdx.x;
    const int bid = blockIdx.x;
    const unsigned nbk = gridDim.x;
    const int stride = (int)nbk * BLK;
    unsigned* bar = sc + 8;           // zeroed by host memset
    unsigned ph = 0;

    // ---------------- phase 0 + A: 12-bit histogram ----------------
    if (bid == 0) {
        for (int i = tid; i < NB1; i += BLK) hist_a[i] = 0u;
        for (int i = tid; i < NB2; i += BLK) hist_b[i] = 0u;
        for (int i = tid; i < NB3; i += BLK) hist_c[i] = 0u;
    }
    for (int i = tid; i < 2 * NB1; i += BLK) (&lh[0][0])[i] = 0u;
    __syncthreads();
    unsigned* my = lh[(tid >> 7) & 1];
    const float4* x4 = (const float4*)x;
    for (int i = bid * BLK + tid; i < n4; i += stride) {
        float4 v = x4[i];
        atomicAdd(&my[f2u(v.x) >> 20], 1u);
        atomicAdd(&my[f2u(v.y) >> 20], 1u);
        atomicAdd(&my[f2u(v.z) >> 20], 1u);
        atomicAdd(&my[f2u(v.w) >> 20], 1u);
    }
    const long long t0 = (long long)n4 * 4;
    const int ntail = (int)(N - t0);
    if (bid == 0 && tid < ntail) atomicAdd(&my[f2u(x[t0 + tid]) >> 20], 1u);

    gsync(bar, ++ph * nbk);           // (1) hist zeros visible

    for (int i = tid; i < NB1; i += BLK) {
        unsigned s = lh[0][i] + lh[1][i];
        if (s) atomicAdd(&hist_a[i], s);
    }
    gsync(bar, ++ph * nbk);           // (2) hist_a complete

    // ---------------- scan A (every block, redundantly) ----------------
    unsigned b1, krem;
    {
        unsigned loc[16], partial = 0u;
#pragma unroll
        for (int i = 0; i < 16; ++i) { loc[i] = hist_a[NB1 - 1 - (tid * 16 + i)]; partial += loc[i]; }
        unsigned cum = block_exscan256(partial, slds, tid);
#pragma unroll
        for (int i = 0; i < 16; ++i) {
            unsigned c = loc[i];
            if (cum < k && cum + c >= k) { sb[0] = (unsigned)(NB1 - 1 - (tid * 16 + i)); sb[1] = k - cum; }
            cum += c;
        }
        __syncthreads();
        b1 = sb[0]; krem = sb[1];
    }
    __syncthreads();

    // ---------------- phase B: scatter + candidate collection ----------------
    if (tid == 0) sb[2] = 0u;
    __syncthreads();
    auto stage = [&](unsigned u, unsigned idxv) {
        unsigned p = atomicAdd(&sb[2], 1u);
        if (p < STAGE_CAP) { lh[0][p] = u; lh[1][p] = idxv; }
        else { unsigned q = atomicAdd(&sc[4], 1u);
               if (q < cand_cap) { cand_u[q] = u; cand_idx[q] = idxv; } }
    };
    float4* o4 = (float4*)out;
    for (int i = bid * BLK + tid; i < n4; i += stride) {
        float4 v = x4[i];
        unsigned u0 = f2u(v.x), u1 = f2u(v.y), u2 = f2u(v.z), u3 = f2u(v.w);
        float4 o;
        o.x = ((u0 >> 20) > b1) ? v.x : 0.0f;
        o.y = ((u1 >> 20) > b1) ? v.y : 0.0f;
        o.z = ((u2 >> 20) > b1) ? v.z : 0.0f;
        o.w = ((u3 >> 20) > b1) ? v.w : 0.0f;
        o4[i] = o;
        if (((u0 >> 20) == b1) | ((u1 >> 20) == b1) | ((u2 >> 20) == b1) | ((u3 >> 20) == b1)) {
            unsigned base = (unsigned)i * 4u;
            if ((u0 >> 20) == b1) stage(u0, base + 0u);
            if ((u1 >> 20) == b1) stage(u1, base + 1u);
            if ((u2 >> 20) == b1) stage(u2, base + 2u);
            if ((u3 >> 20) == b1) stage(u3, base + 3u);
        }
    }
    if (bid == 0 && tid < ntail) {
        long long idx = t0 + tid;
        float v = x[idx];
        unsigned u = f2u(v);
        out[idx] = ((u >> 20) > b1) ? v : 0.0f;
        if ((u >> 20) == b1) stage(u, (unsigned)idx);
    }
    __syncthreads();
    unsigned bc = sb[2]; if (bc > STAGE_CAP) bc = STAGE_CAP;
    if (tid == 0) sb[3] = atomicAdd(&sc[4], bc);   // one global atomic per block
    __syncthreads();
    {
        unsigned gbase = sb[3];
        for (unsigned j = (unsigned)tid; j < bc; j += BLK) {
            unsigned p = gbase + j;
            if (p < cand_cap) { cand_u[p] = lh[0][j]; cand_idx[p] = lh[1][j]; }
        }
    }
    gsync(bar, ++ph * nbk);           // (3) out + candidate list complete

    // ---------------- C1: bits 19..10 over candidates ----------------
    unsigned m = sc[4]; if (m > cand_cap) m = cand_cap;
    for (int i = tid; i < NB2; i += BLK) { lh[0][i] = 0u; lh[1][i] = 0u; }
    __syncthreads();
    for (unsigned j = (unsigned)(bid * BLK + tid); j < m; j += (unsigned)stride) {
        unsigned u = cand_u[j];
        atomicAdd(&my[(u >> 10) & 1023u], 1u);
    }
    __syncthreads();
    for (int i = tid; i < NB2; i += BLK) {
        unsigned s = lh[0][i] + lh[1][i];
        if (s) atomicAdd(&hist_b[i], s);
    }
    gsync(bar, ++ph * nbk);           // (4) hist_b complete

    unsigned b2, krem2;
    {
        unsigned loc[4], partial = 0u;
#pragma unroll
        for (int i = 0; i < 4; ++i) { loc[i] = hist_b[NB2 - 1 - (tid * 4 + i)]; partial += loc[i]; }
        unsigned cum = block_exscan256(partial, slds, tid);
#pragma unroll
        for (int i = 0; i < 4; ++i) {
            unsigned c = loc[i];
            if (cum < krem && cum + c >= krem) { sb[0] = (unsigned)(NB2 - 1 - (tid * 4 + i)); sb[1] = krem - cum; }
            cum += c;
        }
        __syncthreads();
        b2 = sb[0]; krem2 = sb[1];
    }
    __syncthreads();

    // ---------------- C2: bits 9..0, filtered ----------------
    for (int i = tid; i < NB3; i += BLK) { lh[0][i] = 0u; lh[1][i] = 0u; }
    __syncthreads();
    for (unsigned j = (unsigned)(bid * BLK + tid); j < m; j += (unsigned)stride) {
        unsigned u = cand_u[j];
        if (((u >> 10) & 1023u) == b2) atomicAdd(&my[u & 1023u], 1u);
    }
    __syncthreads();
    for (int i = tid; i < NB3; i += BLK) {
        unsigned s = lh[0][i] + lh[1][i];
        if (s) atomicAdd(&hist_c[i], s);
    }
    gsync(bar, ++ph * nbk);           // (5) hist_c complete

    unsigned b3, needeq;
    {
        unsigned loc[4], partial = 0u;
#pragma unroll
        for (int i = 0; i < 4; ++i) { loc[i] = hist_c[NB3 - 1 - (tid * 4 + i)]; partial += loc[i]; }
        unsigned cum = block_exscan256(partial, slds, tid);
#pragma unroll
        for (int i = 0; i < 4; ++i) {
            unsigned c = loc[i];
            if (cum < krem2 && cum + c >= krem2) { sb[0] = (unsigned)(NB3 - 1 - (tid * 4 + i)); sb[1] = krem2 - cum; }
            cum += c;
        }
        __syncthreads();
        b3 = sb[0]; needeq = sb[1];
    }
    const unsigned tu = (b1 << 20) | (b2 << 10) | b3;

    // ---------------- D: write selected candidates ----------------
    for (unsigned j = (unsigned)(bid * BLK + tid); j < m; j += (unsigned)stride) {
        unsigned u = cand_u[j];
        if (u > tu) out[cand_idx[j]] = u2f(u);
        else if (u == tu) {
            unsigned q = atomicAdd(&sc[5], 1u);
            if (q < EQ_CAP) eq_list[q] = cand_idx[j];
        }
    }
    gsync(bar, ++ph * nbk);           // (6) eq_list complete

    // ---------------- E: stable tie-break (smallest indices) ----------------
    if (bid == 0) {
        unsigned me = sc[5]; if (me > EQ_CAP) me = EQ_CAP;
        float f = u2f(tu);
        for (unsigned j = (unsigned)tid; j < me; j += BLK) {
            unsigned idxv = eq_list[j];
            unsigned cnt = 0u;
            for (unsigned l = 0; l < me; ++l) cnt += (eq_list[l] < idxv) ? 1u : 0u;
            if (cnt < needeq) out[idxv] = f;
        }
    }
}

extern "C" void kernel_launch(void* const* d_in, const int* in_sizes, int n_in,
                              void* d_out, int out_size, void* d_ws, size_t ws_size,
                              hipStream_t stream) {
    const float* x = (const float*)d_in[0];
    float* out = (float*)d_out;
    long long N = (long long)in_sizes[0];
    int n4 = (int)(N >> 2);
    unsigned k = (unsigned)((double)N * 0.1);
    if (k == 0u) k = 1u;

    uint8_t* w = (uint8_t*)d_ws;
    unsigned* sc      = (unsigned*)(w);                                 // 256 B (incl. barrier)
    unsigned* hist_a  = (unsigned*)(w + 256);                           // 16 KB
    unsigned* hist_b  = (unsigned*)(w + 256 + 16384);                   // 4 KB
    unsigned* hist_c  = (unsigned*)(w + 256 + 16384 + 4096);            // 4 KB
    unsigned* eq_list = (unsigned*)(w + 256 + 16384 + 4096 + 4096);     // 256 KB
    size_t fixed = 256 + 16384 + 4096 + 4096 + (size_t)EQ_CAP * 4;
    size_t rem = (ws_size > fixed) ? (ws_size - fixed) : 0;
    size_t cap_sz = rem / 8;                                            // (u,idx) pairs
    if (cap_sz > (size_t)(8u << 20)) cap_sz = (size_t)(8u << 20);
    unsigned cand_cap = (unsigned)cap_sz;
    unsigned* cand_u   = (unsigned*)(w + fixed);
    unsigned* cand_idx = cand_u + cand_cap;

    // Grid sized for guaranteed co-residency (manual grid barrier inside).
    static int g_grid = 0;
    if (g_grid == 0) {
        int nb = 0;
        if (hipOccupancyMaxActiveBlocksPerMultiprocessor(&nb, (const void*)topk_fused,
                                                         BLK, 0) != hipSuccess || nb < 1)
            nb = 4;  // static analysis: 33.8 KB LDS -> 4 blocks/CU
        int dev = 0; hipGetDevice(&dev);
        int ncu = 0;
        if (hipDeviceGetAttribute(&ncu, hipDeviceAttributeMultiprocessorCount, dev) != hipSuccess || ncu < 1)
            ncu = 256;
        long long g = (long long)nb * (long long)ncu;
        if (g > MAXGRID) g = MAXGRID;
        if (g < 1) g = 1;
        g_grid = (int)g;
    }

    hipMemsetAsync(sc, 0, 256, stream);   // zero scalars + barrier counter
    hipLaunchKernelGGL(topk_fused, dim3(g_grid), dim3(BLK), 0, stream,
                       x, out, N, n4, k, sc, hist_a, hist_b, hist_c,
                       cand_u, cand_idx, cand_cap, eq_list);
}

// Round 2
// 559.178 us; speedup vs baseline: 2.0869x; 2.0869x over previous
//
#include <hip/hip_runtime.h>
#include <stdint.h>

// Fused single-kernel top-k (k = 10% of N) by value over flat fp32.
// FENCELESS device-wide barriers: no __threadfence (agent fences emit
// buffer_wbl2/buffer_inv L2 flushes; 6 barriers x 1024 blocks of those was
// ~800us of idle in round 1). Instead, NO bulk plain data crosses a barrier:
//   - histograms: device-scope atomicAdd (performed at L3) -> read back with
//     relaxed agent-scope atomic loads (sc1, bypass possibly-stale L2).
//     Zeroed by host memset (kernel-boundary flush makes that coherent).
//   - candidates: block-PRIVATE (LDS staging); phases C/D use own candidates
//     only. Global overflow flag -> full-rescan fallback for correctness.
//   - out: single-writer-per-dword. B writes non-candidate dwords; D (same
//     block that staged) writes candidate dwords != t_u; E (block 0) writes
//     all == t_u dwords. No dword has two writers -> no writeback races.
// Barrier = __syncthreads (drains vmcnt: release) + relaxed agent atomic
// add/spin on a counter. Cost ~ arrival skew only.
//
// Phases: A 12-bit hist | scanA | B scatter+stage | C1 hist(b19..10) | scanB
//         | C2 hist(b9..0) | scanC -> t_u | D own-candidate writes | E ties.

#define BLK       256
#define MAXGRID   1024
#define NB1       4096   // top 12 bits
#define NBC       1024   // 10-bit sub-histograms
#define STAGE_CAP 3072   // per-block candidate cap (mean ~690 on N(0,1))
#define EQ_CAP    65536

__device__ __forceinline__ unsigned f2u(float x) {
    unsigned b = __float_as_uint(x);
    return (b & 0x80000000u) ? ~b : (b | 0x80000000u);
}
__device__ __forceinline__ float u2f(unsigned u) {
    return __uint_as_float((u & 0x80000000u) ? (u & 0x7FFFFFFFu) : ~u);
}
// Coherent (L2-bypassing) accesses for small cross-block data.
__device__ __forceinline__ unsigned cload(const unsigned* p) {
    return __hip_atomic_load(p, __ATOMIC_RELAXED, __HIP_MEMORY_SCOPE_AGENT);
}
__device__ __forceinline__ void cstore(unsigned* p, unsigned v) {
    __hip_atomic_store(p, v, __ATOMIC_RELAXED, __HIP_MEMORY_SCOPE_AGENT);
}

// Fenceless grid barrier. __syncthreads() drains vmcnt(0) per wave (compiler
// semantics), so all prior atomics/sc1-ops reached L3 before arrival.
__device__ __forceinline__ void gsync(unsigned* bar, unsigned target) {
    __syncthreads();
    if (threadIdx.x == 0) {
        __hip_atomic_fetch_add(bar, 1u, __ATOMIC_RELAXED, __HIP_MEMORY_SCOPE_AGENT);
        unsigned spins = 0u;
        while (cload(bar) < target) {
            __builtin_amdgcn_s_sleep(32);
            if (++spins > 600000u) break;   // ~0.5s failsafe
        }
    }
    __syncthreads();
}

__device__ __forceinline__ unsigned block_exscan256(unsigned v,
                                                    volatile unsigned* lds,
                                                    int tid)
{
    lds[tid] = v;
    __syncthreads();
    for (int off = 1; off < 256; off <<= 1) {
        unsigned t = (tid >= off) ? lds[tid - off] : 0u;
        __syncthreads();
        lds[tid] += t;
        __syncthreads();
    }
    unsigned incl = lds[tid];
    return incl - v;
}

__global__ void __launch_bounds__(BLK, 4)
topk_fused(const float* __restrict__ x, float* __restrict__ out,
           long long N, int n4, unsigned k,
           unsigned* __restrict__ sc,
           unsigned* __restrict__ hist_a, unsigned* __restrict__ hist_b,
           unsigned* __restrict__ hist_c, unsigned* __restrict__ eq_list)
{
    // 32 KB, time-shared: phase A = 2 hist copies (2x4096);
    // phases B..D = su[3072] | si[3072] | chist[2048 = 2x1024 copies]
    __shared__ unsigned lh[2 * NB1];
    __shared__ unsigned slds[BLK];
    __shared__ unsigned sb[8];

    const int tid = threadIdx.x;
    const int bid = blockIdx.x;
    const unsigned nbk = gridDim.x;
    const int stride = (int)nbk * BLK;
    unsigned* bar = sc + 32;          // own cache line (offset 128 B)
    unsigned ph = 0;

    const float4* x4 = (const float4*)x;
    float4* o4 = (float4*)out;
    const long long t0 = (long long)n4 * 4;
    const int ntail = (int)(N - t0);

    // ---------------- A: 12-bit histogram ----------------
    for (int i = tid; i < 2 * NB1; i += BLK) lh[i] = 0u;
    __syncthreads();
    {
        unsigned* my = lh + ((tid >> 7) & 1) * NB1;
        for (int i = bid * BLK + tid; i < n4; i += stride) {
            float4 v = x4[i];
            atomicAdd(&my[f2u(v.x) >> 20], 1u);
            atomicAdd(&my[f2u(v.y) >> 20], 1u);
            atomicAdd(&my[f2u(v.z) >> 20], 1u);
            atomicAdd(&my[f2u(v.w) >> 20], 1u);
        }
        if (bid == 0 && tid < ntail) atomicAdd(&my[f2u(x[t0 + tid]) >> 20], 1u);
    }
    __syncthreads();
    for (int i = tid; i < NB1; i += BLK) {
        unsigned s = lh[i] + lh[NB1 + i];
        if (s) atomicAdd(&hist_a[i], s);      // device scope -> L3
    }
    gsync(bar, ++ph * nbk);                   // (1) hist_a complete

    // ---------------- scan A (all blocks, redundant) ----------------
    unsigned b1, krem;
    {
        unsigned loc[16], partial = 0u;
#pragma unroll
        for (int i = 0; i < 16; ++i) {
            loc[i] = cload(&hist_a[NB1 - 1 - (tid * 16 + i)]);
            partial += loc[i];
        }
        unsigned cum = block_exscan256(partial, slds, tid);
#pragma unroll
        for (int i = 0; i < 16; ++i) {
            unsigned c = loc[i];
            if (cum < k && cum + c >= k) { sb[0] = (unsigned)(NB1 - 1 - (tid * 16 + i)); sb[1] = k - cum; }
            cum += c;
        }
        __syncthreads();
        b1 = sb[0]; krem = sb[1];
    }
    __syncthreads();

    // ---------------- B: scatter non-candidates + stage own candidates ----
    if (tid == 0) sb[2] = 0u;
    __syncthreads();
    unsigned* su = lh;                 // candidate sortable-u32
    unsigned* si = lh + STAGE_CAP;     // candidate flat index
    auto stage = [&](unsigned u, unsigned idxv) {
        unsigned p = atomicAdd(&sb[2], 1u);
        if (p < STAGE_CAP) { su[p] = u; si[p] = idxv; }
        else cstore(&sc[7], 1u);       // overflow -> global flag
    };
    for (int i = bid * BLK + tid; i < n4; i += stride) {
        float4 v = x4[i];
        unsigned u0 = f2u(v.x), u1 = f2u(v.y), u2 = f2u(v.z), u3 = f2u(v.w);
        bool c0 = (u0 >> 20) == b1, c1 = (u1 >> 20) == b1,
             c2 = (u2 >> 20) == b1, c3 = (u3 >> 20) == b1;
        float4 o;
        o.x = ((u0 >> 20) > b1) ? v.x : 0.0f;
        o.y = ((u1 >> 20) > b1) ? v.y : 0.0f;
        o.z = ((u2 >> 20) > b1) ? v.z : 0.0f;
        o.w = ((u3 >> 20) > b1) ? v.w : 0.0f;
        if (!(c0 | c1 | c2 | c3)) {
            o4[i] = o;                           // fast path: whole quad
        } else {                                 // skip candidate dwords
            unsigned base = (unsigned)i * 4u;
            if (c0) stage(u0, base + 0u); else out[base + 0u] = o.x;
            if (c1) stage(u1, base + 1u); else out[base + 1u] = o.y;
            if (c2) stage(u2, base + 2u); else out[base + 2u] = o.z;
            if (c3) stage(u3, base + 3u); else out[base + 3u] = o.w;
        }
    }
    if (bid == 0 && tid < ntail) {
        long long idx = t0 + tid;
        float v = x[idx];
        unsigned u = f2u(v);
        if ((u >> 20) == b1) stage(u, (unsigned)idx);
        else out[idx] = ((u >> 20) > b1) ? v : 0.0f;
    }
    __syncthreads();
    unsigned mycnt = sb[2]; if (mycnt > STAGE_CAP) mycnt = STAGE_CAP;
    gsync(bar, ++ph * nbk);                   // (2) overflow flag visible
    const bool ovf = (cload(&sc[7]) != 0u);

    // ---------------- C1: bits 19..10 ----------------
    unsigned* chist = lh + 2 * STAGE_CAP;     // 2048 words
    unsigned* chm = chist + ((tid >> 7) & 1) * NBC;
    for (int i = tid; i < 2 * NBC; i += BLK) chist[i] = 0u;
    __syncthreads();
    if (!ovf) {
        for (unsigned j = (unsigned)tid; j < mycnt; j += BLK) {
            unsigned u = su[j];
            atomicAdd(&chm[(u >> 10) & 1023u], 1u);
        }
    } else {
        for (int i = bid * BLK + tid; i < n4; i += stride) {
            float4 v = x4[i];
            unsigned u;
            u = f2u(v.x); if ((u >> 20) == b1) atomicAdd(&chm[(u >> 10) & 1023u], 1u);
            u = f2u(v.y); if ((u >> 20) == b1) atomicAdd(&chm[(u >> 10) & 1023u], 1u);
            u = f2u(v.z); if ((u >> 20) == b1) atomicAdd(&chm[(u >> 10) & 1023u], 1u);
            u = f2u(v.w); if ((u >> 20) == b1) atomicAdd(&chm[(u >> 10) & 1023u], 1u);
        }
        if (bid == 0 && tid < ntail) {
            unsigned u = f2u(x[t0 + tid]);
            if ((u >> 20) == b1) atomicAdd(&chm[(u >> 10) & 1023u], 1u);
        }
    }
    __syncthreads();
    for (int i = tid; i < NBC; i += BLK) {
        unsigned s = chist[i] + chist[NBC + i];
        if (s) atomicAdd(&hist_b[i], s);
    }
    gsync(bar, ++ph * nbk);                   // (3) hist_b complete

    unsigned b2, krem2;
    {
        unsigned loc[4], partial = 0u;
#pragma unroll
        for (int i = 0; i < 4; ++i) {
            loc[i] = cload(&hist_b[NBC - 1 - (tid * 4 + i)]);
            partial += loc[i];
        }
        unsigned cum = block_exscan256(partial, slds, tid);
#pragma unroll
        for (int i = 0; i < 4; ++i) {
            unsigned c = loc[i];
            if (cum < krem && cum + c >= krem) { sb[0] = (unsigned)(NBC - 1 - (tid * 4 + i)); sb[1] = krem - cum; }
            cum += c;
        }
        __syncthreads();
        b2 = sb[0]; krem2 = sb[1];
    }
    __syncthreads();

    // ---------------- C2: bits 9..0, filtered ----------------
    for (int i = tid; i < 2 * NBC; i += BLK) chist[i] = 0u;
    __syncthreads();
    if (!ovf) {
        for (unsigned j = (unsigned)tid; j < mycnt; j += BLK) {
            unsigned u = su[j];
            if (((u >> 10) & 1023u) == b2) atomicAdd(&chm[u & 1023u], 1u);
        }
    } else {
        for (int i = bid * BLK + tid; i < n4; i += stride) {
            float4 v = x4[i];
            unsigned u;
            u = f2u(v.x); if ((u >> 20) == b1 && ((u >> 10) & 1023u) == b2) atomicAdd(&chm[u & 1023u], 1u);
            u = f2u(v.y); if ((u >> 20) == b1 && ((u >> 10) & 1023u) == b2) atomicAdd(&chm[u & 1023u], 1u);
            u = f2u(v.z); if ((u >> 20) == b1 && ((u >> 10) & 1023u) == b2) atomicAdd(&chm[u & 1023u], 1u);
            u = f2u(v.w); if ((u >> 20) == b1 && ((u >> 10) & 1023u) == b2) atomicAdd(&chm[u & 1023u], 1u);
        }
        if (bid == 0 && tid < ntail) {
            unsigned u = f2u(x[t0 + tid]);
            if ((u >> 20) == b1 && ((u >> 10) & 1023u) == b2) atomicAdd(&chm[u & 1023u], 1u);
        }
    }
    __syncthreads();
    for (int i = tid; i < NBC; i += BLK) {
        unsigned s = chist[i] + chist[NBC + i];
        if (s) atomicAdd(&hist_c[i], s);
    }
    gsync(bar, ++ph * nbk);                   // (4) hist_c complete

    unsigned b3, needeq;
    {
        unsigned loc[4], partial = 0u;
#pragma unroll
        for (int i = 0; i < 4; ++i) {
            loc[i] = cload(&hist_c[NBC - 1 - (tid * 4 + i)]);
            partial += loc[i];
        }
        unsigned cum = block_exscan256(partial, slds, tid);
#pragma unroll
        for (int i = 0; i < 4; ++i) {
            unsigned c = loc[i];
            if (cum < krem2 && cum + c >= krem2) { sb[0] = (unsigned)(NBC - 1 - (tid * 4 + i)); sb[1] = krem2 - cum; }
            cum += c;
        }
        __syncthreads();
        b3 = sb[0]; needeq = sb[1];
    }
    const unsigned tu = (b1 << 20) | (b2 << 10) | b3;

    // ---------------- D: write own candidates (single writer per dword) ---
    if (!ovf) {
        for (unsigned j = (unsigned)tid; j < mycnt; j += BLK) {
            unsigned u = su[j], idxv = si[j];
            if (u > tu)      out[idxv] = u2f(u);
            else if (u < tu) out[idxv] = 0.0f;
            else { unsigned q = atomicAdd(&sc[5], 1u); if (q < EQ_CAP) cstore(&eq_list[q], idxv); }
        }
    } else {
        for (int i = bid * BLK + tid; i < n4; i += stride) {
            float4 v = x4[i];
            unsigned base = (unsigned)i * 4u;
            unsigned uu[4] = { f2u(v.x), f2u(v.y), f2u(v.z), f2u(v.w) };
#pragma unroll
            for (int l = 0; l < 4; ++l) {
                unsigned u = uu[l];
                if ((u >> 20) == b1) {
                    if (u > tu)      out[base + l] = u2f(u);
                    else if (u < tu) out[base + l] = 0.0f;
                    else { unsigned q = atomicAdd(&sc[5], 1u); if (q < EQ_CAP) cstore(&eq_list[q], base + (unsigned)l); }
                }
            }
        }
        if (bid == 0 && tid < ntail) {
            long long idx = t0 + tid;
            unsigned u = f2u(x[idx]);
            if ((u >> 20) == b1) {
                if (u > tu)      out[idx] = u2f(u);
                else if (u < tu) out[idx] = 0.0f;
                else { unsigned q = atomicAdd(&sc[5], 1u); if (q < EQ_CAP) cstore(&eq_list[q], (unsigned)idx); }
            }
        }
    }
    gsync(bar, ++ph * nbk);                   // (5) eq_list complete

    // ---------------- E: ties (block 0 is sole writer of ==t_u dwords) ----
    if (bid == 0) {
        unsigned m = cload(&sc[5]); if (m > EQ_CAP) m = EQ_CAP;
        float f = u2f(tu);
        if (m <= needeq) {
            for (unsigned j = (unsigned)tid; j < m; j += BLK)
                out[cload(&eq_list[j])] = f;
        } else {
            for (unsigned j = (unsigned)tid; j < m; j += BLK) {
                unsigned idxv = cload(&eq_list[j]);
                unsigned cnt = 0u;
                for (unsigned l = 0; l < m; ++l)
                    cnt += (cload(&eq_list[l]) < idxv) ? 1u : 0u;
                out[idxv] = (cnt < needeq) ? f : 0.0f;   // stable: smallest idx win
            }
        }
    }
}

extern "C" void kernel_launch(void* const* d_in, const int* in_sizes, int n_in,
                              void* d_out, int out_size, void* d_ws, size_t ws_size,
                              hipStream_t stream) {
    const float* x = (const float*)d_in[0];
    float* out = (float*)d_out;
    long long N = (long long)in_sizes[0];
    int n4 = (int)(N >> 2);
    unsigned k = (unsigned)((double)N * 0.1);
    if (k == 0u) k = 1u;

    uint8_t* w = (uint8_t*)d_ws;
    unsigned* sc      = (unsigned*)(w);                              // 256 B (bar @ +128)
    unsigned* hist_a  = (unsigned*)(w + 256);                        // 16 KB
    unsigned* hist_b  = (unsigned*)(w + 256 + 16384);                // 4 KB
    unsigned* hist_c  = (unsigned*)(w + 256 + 16384 + 4096);         // 4 KB
    unsigned* eq_list = (unsigned*)(w + 256 + 16384 + 4096 + 4096);  // 256 KB
    const size_t zbytes = 256 + 16384 + 4096 + 4096;

    // Grid sized for guaranteed co-residency (grid barrier inside).
    static int g_grid = 0;
    if (g_grid == 0) {
        int nb = 0;
        if (hipOccupancyMaxActiveBlocksPerMultiprocessor(&nb, (const void*)topk_fused,
                                                         BLK, 0) != hipSuccess || nb < 1)
            nb = 4;   // 33.8 KB LDS -> 4 blocks/CU
        int dev = 0; hipGetDevice(&dev);
        int ncu = 0;
        if (hipDeviceGetAttribute(&ncu, hipDeviceAttributeMultiprocessorCount, dev) != hipSuccess || ncu < 1)
            ncu = 256;
        long long g = (long long)nb * (long long)ncu;
        if (g > MAXGRID) g = MAXGRID;
        if (g < 1) g = 1;
        g_grid = (int)g;
    }

    hipMemsetAsync(w, 0, zbytes, stream);   // sc + barrier + all histograms
    hipLaunchKernelGGL(topk_fused, dim3(g_grid), dim3(BLK), 0, stream,
                       x, out, N, n4, k, sc, hist_a, hist_b, hist_c, eq_list);
}

// Round 4
// 335.782 us; speedup vs baseline: 3.4753x; 1.6653x over previous
//
#include <hip/hip_runtime.h>
#include <stdint.h>

// Fused single-kernel top-k (k = 10% of N) by value over flat fp32.
// Round-4: same as round-3 design (hierarchical fenceless grid barrier,
// 3 barriers common path), with the nontemporal-store compile fix:
// __builtin_nontemporal_store needs a NATIVE vector type, not HIP float4.
//
// Round-2 post-mortem: single-counter barrier = 1024 same-dword agent atomics
// + 1024 spinners polling the same L3 bank -> arrival RMWs starved behind
// spin reads, ~50-60us per barrier (~250us of the 414us total). Fix:
//   - 16 arrival counters (one per 64-block group, 256B apart)
//   - group-complete leaders bump one global group counter
//   - last leader writes 16 per-group release words; blocks spin on OWN
//     group's word only (64 spinners/line, s_sleep(16) ~0.4us polls)
// Data-flow discipline (no fences needed):
//   - cross-block small data via device-scope atomics (L3) + sc1 loads
//   - candidates are block-private in LDS
//   - out has a single writer per dword
// Phases (common path, 3 barriers):
//   A: 12-bit hist (LDS 2 copies -> device atomics)            [read x]
//   (1) | scanA -> b1,krem
//   B: scatter non-candidates (NT stores), stage own candidates in LDS,
//      + C1: hist bits 19..10 of own candidates -> hist_b      [read x(L2/L3), write out]
//   (2) | scanB -> b2,krem2
//   C2: hist bits 9..0 of own candidates -> hist_c
//   (3) | scanC -> t_u, need_eq, c_b3
//   D: write own candidates; if need_eq == c_b3 ties written directly (no E)
//   [rare: (4) + E tie-break by block 0; rare overflow: full-rescan fallback]

#define BLK       256
#define MAXGRID   1024
#define NB1       4096   // top 12 bits
#define NBC       1024   // 10-bit sub-histograms
#define STAGE_CAP 3072   // per-block candidate cap (mean ~690 on N(0,1))
#define EQ_CAP    65536
#define GRP_SHIFT 6      // 64 blocks per barrier group
#define LSTRIDE   64     // dwords (256 B) between barrier lines

typedef float vf4 __attribute__((ext_vector_type(4)));

__device__ __forceinline__ unsigned f2u(float x) {
    unsigned b = __float_as_uint(x);
    return (b & 0x80000000u) ? ~b : (b | 0x80000000u);
}
__device__ __forceinline__ float u2f(unsigned u) {
    return __uint_as_float((u & 0x80000000u) ? (u & 0x7FFFFFFFu) : ~u);
}
__device__ __forceinline__ unsigned cload(const unsigned* p) {
    return __hip_atomic_load(p, __ATOMIC_RELAXED, __HIP_MEMORY_SCOPE_AGENT);
}
__device__ __forceinline__ void cstore(unsigned* p, unsigned v) {
    __hip_atomic_store(p, v, __ATOMIC_RELAXED, __HIP_MEMORY_SCOPE_AGENT);
}

// Hierarchical fenceless grid barrier. Monotonic epoch counters, no reset.
// __syncthreads() drains vmcnt before arrival (release); device-scope atomic
// data (histograms) is at L3, re-read with sc1 loads (acquire-free).
__device__ __forceinline__ void gsync(unsigned* bw, unsigned ep, unsigned nbk) {
    __syncthreads();
    if (threadIdx.x == 0) {
        const unsigned g  = (unsigned)blockIdx.x >> GRP_SHIFT;
        const unsigned ng = (nbk + ((1u << GRP_SHIFT) - 1u)) >> GRP_SHIFT;
        unsigned* arr = bw;                        // arr[g*LSTRIDE]
        unsigned* gar = bw + 1024;                 // own line
        unsigned* rel = bw + 1088;                 // rel[g*LSTRIDE]
        unsigned grp0 = g << GRP_SHIFT;
        unsigned cnt_g = nbk - grp0;
        if (cnt_g > (1u << GRP_SHIFT)) cnt_g = (1u << GRP_SHIFT);
        unsigned old = __hip_atomic_fetch_add(&arr[g * LSTRIDE], 1u,
                                              __ATOMIC_RELAXED, __HIP_MEMORY_SCOPE_AGENT);
        if (old == ep * cnt_g - 1u) {              // last arrival in group
            unsigned og = __hip_atomic_fetch_add(gar, 1u,
                                                 __ATOMIC_RELAXED, __HIP_MEMORY_SCOPE_AGENT);
            if (og == ep * ng - 1u) {              // last group: release all
                for (unsigned i = 0; i < ng; ++i)
                    cstore(&rel[i * LSTRIDE], ep);
            }
        }
        unsigned spins = 0u;
        while (cload(&rel[g * LSTRIDE]) < ep) {
            __builtin_amdgcn_s_sleep(16);          // ~0.4 us polls, 64 spinners/line
            if (++spins > 1500000u) break;         // ~0.7 s failsafe
        }
    }
    __syncthreads();
}

__device__ __forceinline__ unsigned block_exscan256(unsigned v,
                                                    volatile unsigned* lds,
                                                    int tid)
{
    lds[tid] = v;
    __syncthreads();
    for (int off = 1; off < 256; off <<= 1) {
        unsigned t = (tid >= off) ? lds[tid - off] : 0u;
        __syncthreads();
        lds[tid] += t;
        __syncthreads();
    }
    unsigned incl = lds[tid];
    return incl - v;
}

// Descending scan over NB bins (device hist read with sc1 loads).
// Writes sb[0]=bin, sb[1]=k-cum (remaining), sb[2]=bin count.
template<int NB, int PT>
__device__ void scan_desc(const unsigned* h, unsigned kin,
                          volatile unsigned* slds, unsigned* sb, int tid)
{
    unsigned loc[PT], partial = 0u;
#pragma unroll
    for (int i = 0; i < PT; ++i) {
        loc[i] = cload(&h[NB - 1 - (tid * PT + i)]);
        partial += loc[i];
    }
    unsigned cum = block_exscan256(partial, slds, tid);
#pragma unroll
    for (int i = 0; i < PT; ++i) {
        unsigned c = loc[i];
        if (cum < kin && cum + c >= kin) {
            sb[0] = (unsigned)(NB - 1 - (tid * PT + i));
            sb[1] = kin - cum;
            sb[2] = c;
        }
        cum += c;
    }
    __syncthreads();
}

__global__ void __launch_bounds__(BLK, 4)
topk_fused(const float* __restrict__ x, float* __restrict__ out,
           long long N, int n4, unsigned k,
           unsigned* __restrict__ sc, unsigned* __restrict__ bw,
           unsigned* __restrict__ hist_a, unsigned* __restrict__ hist_b,
           unsigned* __restrict__ hist_c, unsigned* __restrict__ hist_b2,
           unsigned* __restrict__ hist_c2, unsigned* __restrict__ eq_list)
{
    // 32 KB time-shared: A = 2 hist copies (2x4096);
    // B..D = su[3072] | si[3072] | chist[2048 = 2x1024]
    __shared__ unsigned lh[2 * NB1];
    __shared__ unsigned slds[BLK];
    __shared__ unsigned sb[8];

    const int tid = threadIdx.x;
    const int bid = blockIdx.x;
    const unsigned nbk = gridDim.x;
    const int stride = (int)nbk * BLK;
    unsigned ep = 0;

    const float4* x4 = (const float4*)x;
    const long long t0 = (long long)n4 * 4;
    const int ntail = (int)(N - t0);

    // ---------------- A: 12-bit histogram ----------------
    for (int i = tid; i < 2 * NB1; i += BLK) lh[i] = 0u;
    __syncthreads();
    {
        unsigned* my = lh + ((tid >> 7) & 1) * NB1;
        for (int i = bid * BLK + tid; i < n4; i += stride) {
            float4 v = x4[i];
            atomicAdd(&my[f2u(v.x) >> 20], 1u);
            atomicAdd(&my[f2u(v.y) >> 20], 1u);
            atomicAdd(&my[f2u(v.z) >> 20], 1u);
            atomicAdd(&my[f2u(v.w) >> 20], 1u);
        }
        if (bid == 0 && tid < ntail) atomicAdd(&my[f2u(x[t0 + tid]) >> 20], 1u);
    }
    __syncthreads();
    for (int i = tid; i < NB1; i += BLK) {
        unsigned s = lh[i] + lh[NB1 + i];
        if (s) atomicAdd(&hist_a[i], s);     // device scope -> L3
    }
    gsync(bw, ++ep, nbk);                    // (1) hist_a complete

    scan_desc<NB1, 16>(hist_a, k, slds, sb, tid);
    const unsigned b1 = sb[0], krem = sb[1];
    __syncthreads();

    // ------- B: scatter non-candidates + stage own candidates + C1 -------
    if (tid == 0) sb[3] = 0u;
    __syncthreads();
    unsigned* su = lh;                 // candidate sortable-u32
    unsigned* si = lh + STAGE_CAP;     // candidate flat index
    auto stage = [&](unsigned u, unsigned idxv) {
        unsigned p = atomicAdd(&sb[3], 1u);
        if (p < STAGE_CAP) { su[p] = u; si[p] = idxv; }
        else cstore(&sc[7], 1u);       // overflow -> global flag
    };
    for (int i = bid * BLK + tid; i < n4; i += stride) {
        float4 v = x4[i];
        unsigned u0 = f2u(v.x), u1 = f2u(v.y), u2 = f2u(v.z), u3 = f2u(v.w);
        bool c0 = (u0 >> 20) == b1, c1 = (u1 >> 20) == b1,
             c2 = (u2 >> 20) == b1, c3 = (u3 >> 20) == b1;
        vf4 o;
        o.x = ((u0 >> 20) > b1) ? v.x : 0.0f;
        o.y = ((u1 >> 20) > b1) ? v.y : 0.0f;
        o.z = ((u2 >> 20) > b1) ? v.z : 0.0f;
        o.w = ((u3 >> 20) > b1) ? v.w : 0.0f;
        if (!(c0 | c1 | c2 | c3)) {
            __builtin_nontemporal_store(o, (vf4*)out + i);
        } else {                                 // skip candidate dwords
            unsigned base = (unsigned)i * 4u;
            if (c0) stage(u0, base + 0u); else out[base + 0u] = o.x;
            if (c1) stage(u1, base + 1u); else out[base + 1u] = o.y;
            if (c2) stage(u2, base + 2u); else out[base + 2u] = o.z;
            if (c3) stage(u3, base + 3u); else out[base + 3u] = o.w;
        }
    }
    if (bid == 0 && tid < ntail) {
        long long idx = t0 + tid;
        float v = x[idx];
        unsigned u = f2u(v);
        if ((u >> 20) == b1) stage(u, (unsigned)idx);
        else out[idx] = ((u >> 20) > b1) ? v : 0.0f;
    }
    __syncthreads();
    const unsigned mycnt0 = sb[3];
    const unsigned mycnt = (mycnt0 > STAGE_CAP) ? STAGE_CAP : mycnt0;
    // C1 on own candidates (hist_b garbage if any block overflowed; then
    // the fallback below uses hist_b2 instead).
    unsigned* chist = lh + 2 * STAGE_CAP;     // 2048 words
    unsigned* chm = chist + ((tid >> 7) & 1) * NBC;
    for (int i = tid; i < 2 * NBC; i += BLK) chist[i] = 0u;
    __syncthreads();
    for (unsigned j = (unsigned)tid; j < mycnt; j += BLK)
        atomicAdd(&chm[(su[j] >> 10) & 1023u], 1u);
    __syncthreads();
    for (int i = tid; i < NBC; i += BLK) {
        unsigned s = chist[i] + chist[NBC + i];
        if (s) atomicAdd(&hist_b[i], s);
    }
    gsync(bw, ++ep, nbk);                    // (2) hist_b + ovf flag complete

    const bool ovf = (cload(&sc[7]) != 0u);

    if (!ovf) {
        // ---------------- common path ----------------
        scan_desc<NBC, 4>(hist_b, krem, slds, sb, tid);
        const unsigned b2 = sb[0], krem2 = sb[1];
        __syncthreads();

        // C2: bits 9..0 of own candidates, filtered
        for (int i = tid; i < 2 * NBC; i += BLK) chist[i] = 0u;
        __syncthreads();
        for (unsigned j = (unsigned)tid; j < mycnt; j += BLK) {
            unsigned u = su[j];
            if (((u >> 10) & 1023u) == b2) atomicAdd(&chm[u & 1023u], 1u);
        }
        __syncthreads();
        for (int i = tid; i < NBC; i += BLK) {
            unsigned s = chist[i] + chist[NBC + i];
            if (s) atomicAdd(&hist_c[i], s);
        }
        gsync(bw, ++ep, nbk);                // (3) hist_c complete

        scan_desc<NBC, 4>(hist_c, krem2, slds, sb, tid);
        const unsigned b3 = sb[0], needeq = sb[1], ceq = sb[2];
        const unsigned tu = (b1 << 20) | (b2 << 10) | b3;
        const bool allties = (needeq == ceq);   // uniform across all blocks

        // D: write own candidates (single writer per dword)
        for (unsigned j = (unsigned)tid; j < mycnt; j += BLK) {
            unsigned u = su[j], idxv = si[j];
            if (u > tu)      out[idxv] = u2f(u);
            else if (u < tu) out[idxv] = 0.0f;
            else if (allties) out[idxv] = u2f(u);
            else { unsigned q = atomicAdd(&sc[5], 1u); if (q < EQ_CAP) cstore(&eq_list[q], idxv); }
        }
        if (!allties) {                       // rare: tie-break needed
            gsync(bw, ++ep, nbk);             // (4) eq_list complete
            if (bid == 0) {
                unsigned m = cload(&sc[5]); if (m > EQ_CAP) m = EQ_CAP;
                float f = u2f(tu);
                for (unsigned j = (unsigned)tid; j < m; j += BLK) {
                    unsigned idxv = cload(&eq_list[j]);
                    unsigned cnt = 0u;
                    for (unsigned l = 0; l < m; ++l)
                        cnt += (cload(&eq_list[l]) < idxv) ? 1u : 0u;
                    out[idxv] = (cnt < needeq) ? f : 0.0f;
                }
            }
        }
    } else {
        // ------------- overflow fallback: full-rescan radix -------------
        for (int i = tid; i < 2 * NBC; i += BLK) chist[i] = 0u;
        __syncthreads();
        for (int i = bid * BLK + tid; i < n4; i += stride) {
            float4 v = x4[i];
            unsigned u;
            u = f2u(v.x); if ((u >> 20) == b1) atomicAdd(&chm[(u >> 10) & 1023u], 1u);
            u = f2u(v.y); if ((u >> 20) == b1) atomicAdd(&chm[(u >> 10) & 1023u], 1u);
            u = f2u(v.z); if ((u >> 20) == b1) atomicAdd(&chm[(u >> 10) & 1023u], 1u);
            u = f2u(v.w); if ((u >> 20) == b1) atomicAdd(&chm[(u >> 10) & 1023u], 1u);
        }
        if (bid == 0 && tid < ntail) {
            unsigned u = f2u(x[t0 + tid]);
            if ((u >> 20) == b1) atomicAdd(&chm[(u >> 10) & 1023u], 1u);
        }
        __syncthreads();
        for (int i = tid; i < NBC; i += BLK) {
            unsigned s = chist[i] + chist[NBC + i];
            if (s) atomicAdd(&hist_b2[i], s);
        }
        gsync(bw, ++ep, nbk);
        scan_desc<NBC, 4>(hist_b2, krem, slds, sb, tid);
        const unsigned b2 = sb[0], krem2 = sb[1];
        __syncthreads();

        for (int i = tid; i < 2 * NBC; i += BLK) chist[i] = 0u;
        __syncthreads();
        for (int i = bid * BLK + tid; i < n4; i += stride) {
            float4 v = x4[i];
            unsigned u;
            u = f2u(v.x); if ((u >> 20) == b1 && ((u >> 10) & 1023u) == b2) atomicAdd(&chm[u & 1023u], 1u);
            u = f2u(v.y); if ((u >> 20) == b1 && ((u >> 10) & 1023u) == b2) atomicAdd(&chm[u & 1023u], 1u);
            u = f2u(v.z); if ((u >> 20) == b1 && ((u >> 10) & 1023u) == b2) atomicAdd(&chm[u & 1023u], 1u);
            u = f2u(v.w); if ((u >> 20) == b1 && ((u >> 10) & 1023u) == b2) atomicAdd(&chm[u & 1023u], 1u);
        }
        if (bid == 0 && tid < ntail) {
            unsigned u = f2u(x[t0 + tid]);
            if ((u >> 20) == b1 && ((u >> 10) & 1023u) == b2) atomicAdd(&chm[u & 1023u], 1u);
        }
        __syncthreads();
        for (int i = tid; i < NBC; i += BLK) {
            unsigned s = chist[i] + chist[NBC + i];
            if (s) atomicAdd(&hist_c2[i], s);
        }
        gsync(bw, ++ep, nbk);
        scan_desc<NBC, 4>(hist_c2, krem2, slds, sb, tid);
        const unsigned b3 = sb[0], needeq = sb[1], ceq = sb[2];
        const unsigned tu = (b1 << 20) | (b2 << 10) | b3;
        const bool allties = (needeq == ceq);

        for (int i = bid * BLK + tid; i < n4; i += stride) {
            float4 v = x4[i];
            unsigned base = (unsigned)i * 4u;
            unsigned uu[4] = { f2u(v.x), f2u(v.y), f2u(v.z), f2u(v.w) };
#pragma unroll
            for (int l = 0; l < 4; ++l) {
                unsigned u = uu[l];
                if ((u >> 20) == b1) {
                    if (u > tu)      out[base + l] = u2f(u);
                    else if (u < tu) out[base + l] = 0.0f;
                    else if (allties) out[base + l] = u2f(u);
                    else { unsigned q = atomicAdd(&sc[5], 1u); if (q < EQ_CAP) cstore(&eq_list[q], base + (unsigned)l); }
                }
            }
        }
        if (bid == 0 && tid < ntail) {
            long long idx = t0 + tid;
            unsigned u = f2u(x[idx]);
            if ((u >> 20) == b1) {
                if (u > tu)      out[idx] = u2f(u);
                else if (u < tu) out[idx] = 0.0f;
                else if (allties) out[idx] = u2f(u);
                else { unsigned q = atomicAdd(&sc[5], 1u); if (q < EQ_CAP) cstore(&eq_list[q], (unsigned)idx); }
            }
        }
        if (!allties) {
            gsync(bw, ++ep, nbk);
            if (bid == 0) {
                unsigned m = cload(&sc[5]); if (m > EQ_CAP) m = EQ_CAP;
                float f = u2f(tu);
                for (unsigned j = (unsigned)tid; j < m; j += BLK) {
                    unsigned idxv = cload(&eq_list[j]);
                    unsigned cnt = 0u;
                    for (unsigned l = 0; l < m; ++l)
                        cnt += (cload(&eq_list[l]) < idxv) ? 1u : 0u;
                    out[idxv] = (cnt < needeq) ? f : 0.0f;
                }
            }
        }
    }
}

extern "C" void kernel_launch(void* const* d_in, const int* in_sizes, int n_in,
                              void* d_out, int out_size, void* d_ws, size_t ws_size,
                              hipStream_t stream) {
    const float* x = (const float*)d_in[0];
    float* out = (float*)d_out;
    long long N = (long long)in_sizes[0];
    int n4 = (int)(N >> 2);
    unsigned k = (unsigned)((double)N * 0.1);
    if (k == 0u) k = 1u;

    uint8_t* w = (uint8_t*)d_ws;
    unsigned* sc      = (unsigned*)(w);                  // 256 B scalars
    unsigned* bw      = (unsigned*)(w + 256);            // 12 KB barrier lines
    unsigned* hist_a  = (unsigned*)(w + 256 + 12288);    // 16 KB
    unsigned* hist_b  = hist_a + NB1;                    // 4 KB
    unsigned* hist_c  = hist_b + NBC;                    // 4 KB
    unsigned* hist_b2 = hist_c + NBC;                    // 4 KB
    unsigned* hist_c2 = hist_b2 + NBC;                   // 4 KB
    unsigned* eq_list = hist_c2 + NBC;                   // 256 KB (not zeroed)
    const size_t zbytes = 256 + 12288 + (NB1 + 4 * NBC) * sizeof(unsigned);

    // Grid sized for guaranteed co-residency (grid barrier inside).
    static int g_grid = 0;
    if (g_grid == 0) {
        int nb = 0;
        if (hipOccupancyMaxActiveBlocksPerMultiprocessor(&nb, (const void*)topk_fused,
                                                         BLK, 0) != hipSuccess || nb < 1)
            nb = 4;   // ~33 KB LDS -> 4 blocks/CU
        int dev = 0; (void)hipGetDevice(&dev);
        int ncu = 0;
        if (hipDeviceGetAttribute(&ncu, hipDeviceAttributeMultiprocessorCount, dev) != hipSuccess || ncu < 1)
            ncu = 256;
        long long g = (long long)nb * (long long)ncu;
        if (g > MAXGRID) g = MAXGRID;
        if (g < 1) g = 1;
        g_grid = (int)g;
    }

    (void)hipMemsetAsync(w, 0, zbytes, stream);   // scalars + barrier + histograms
    hipLaunchKernelGGL(topk_fused, dim3(g_grid), dim3(BLK), 0, stream,
                       x, out, N, n4, k, sc, bw,
                       hist_a, hist_b, hist_c, hist_b2, hist_c2, eq_list);
}